// Round 18
// baseline (72.481 us; speedup 1.0000x reference)
//
#include <hip/hip_runtime.h>
#include <hip/hip_bf16.h>
#include <math.h>

#define CHN 192
#define BATCHN 65536
#define NWS 61                        // transformed-weight slots per channel
#define CPB 64                        // channels per block (LDS = 61*64*4 = 15.6 KB)
#define NCG (CHN / CPB)               // 3 channel-groups
#define BLOCKT 256                    // 4 row-groups x 64 channels (4 waves)
#define ROWS_PER_GROUP 16
#define ROWS_PER_BLOCK 64
#define RSLAB 4
#define NSLABS (ROWS_PER_GROUP / RSLAB)        // 4
#define NBLOCKS (NCG * (BATCHN / ROWS_PER_BLOCK))  // 3*1024 = 3072

#define KSCALE 2.885390081777926f    // 2*log2(e)
#define LOG2E  1.4426950408889634f
#define ECLAMP 50.0f                 // exp2-arg clamp: tanh saturates (f32-exact) by ~30;
                                     // with q<=50, Q<=2e17 so Qp*Qm<4e34 << FLT_MAX -> pairing safe

// ---- fast device math -------------------------------------------------------
__device__ __forceinline__ float fast_rcp(float x)  { return __builtin_amdgcn_rcpf(x); }
__device__ __forceinline__ float fast_exp2(float x) { return __builtin_amdgcn_exp2f(x); }

__device__ __forceinline__ float softplus_acc(float h) {
    if (h > 20.0f) return h;
    return log1pf(expf(h));
}

// ============================================================================
// Kernel A (R17 form): parallelized across (channel x layer-unit) = 2304 thr.
// Scaled domain: v' = K*v, K = 2*log2(e); exp2(t') = e^(2t);
// tanh(t) = 1 - 2*rcp(exp2(t')+1).
// L1/L2 fold-t1 form: tq = Sum W v + (BK + T1K);
//   r = rcp(fma(exp2(tq), c1, 1)), c1 = exp2(-T1K);  z = fma(T2, r, tq).
// slot map (ws[s*CHN + c]):
//   0-2  W0K   3-5  B0K   6-8  cp    9-11 cm   12-14 gp  15-17 gm  18-20 T2_0
//   21-29 W1  30-32 BBT1  33-35 C1_1  36-38 T2_1
//   39-47 W2  48-50 BBT2  51-53 C1_2  54-56 T2_2
//   57-59 W3n 60 b3n
// ============================================================================
#define WKTHREADS (12 * CHN)          // 2304
__global__ __launch_bounds__(256) void weights_kernel(
    const float* __restrict__ a0, const float* __restrict__ a1, const float* __restrict__ a2,
    const float* __restrict__ b0, const float* __restrict__ b1, const float* __restrict__ b2,
    const float* __restrict__ b3,
    const float* __restrict__ H0, const float* __restrict__ H1, const float* __restrict__ H2,
    const float* __restrict__ H3,
    float* __restrict__ ws)
{
    const int g = blockIdx.x * 256 + threadIdx.x;
    if (g >= WKTHREADS) return;
    const int c = g % CHN;
    const int u = g / CHN;            // 0..11 (wave-uniform)
    const int l = u / 3, i = u % 3;

    if (l == 0) {
        float w0k  = KSCALE * softplus_acc(H0[c * 3 + i]);
        float h    = 0.5f * w0k;
        float t1k0 = KSCALE * tanhf(a0[c * 3 + i]);
        ws[(0  + i) * CHN + c] = w0k;
        ws[(3  + i) * CHN + c] = KSCALE * b0[c * 3 + i];
        ws[(6  + i) * CHN + c] = exp2f(h);
        ws[(9  + i) * CHN + c] = exp2f(-h);
        ws[(12 + i) * CHN + c] = h + t1k0;
        ws[(15 + i) * CHN + c] = -h + t1k0;
        ws[(18 + i) * CHN + c] = -2.0f * t1k0;
    } else if (l == 1) {
        float t1k1 = KSCALE * tanhf(a1[c * 3 + i]);
        ws[(30 + i) * CHN + c] = KSCALE * b1[c * 3 + i] + t1k1;   // BBT1
        ws[(33 + i) * CHN + c] = exp2f(-t1k1);                    // C1_1
        ws[(36 + i) * CHN + c] = -2.0f * t1k1;                    // T2_1
#pragma unroll
        for (int k = 0; k < 3; ++k)
            ws[(21 + 3 * i + k) * CHN + c] = softplus_acc(H1[c * 9 + 3 * i + k]);
    } else if (l == 2) {
        float t1k2 = KSCALE * tanhf(a2[c * 3 + i]);
        ws[(48 + i) * CHN + c] = KSCALE * b2[c * 3 + i] + t1k2;   // BBT2
        ws[(51 + i) * CHN + c] = exp2f(-t1k2);                    // C1_2
        ws[(54 + i) * CHN + c] = -2.0f * t1k2;                    // T2_2
#pragma unroll
        for (int k = 0; k < 3; ++k)
            ws[(39 + 3 * i + k) * CHN + c] = softplus_acc(H2[c * 9 + 3 * i + k]);
    } else {
        ws[(57 + i) * CHN + c] = -0.5f * softplus_acc(H3[c * 3 + i]);
        if (i == 0) ws[60 * CHN + c] = -LOG2E * b3[c];
    }
}

// ============================================================================
// Kernel B (R18): R15/R17 structure + paired-rcp across the +/- branches.
// rr = rcp(Qp*Qm); rp = Qm*rr; rm = Qp*rr  — 1 rcp serves both branches.
// exp2 inputs clamped at ECLAMP (numerically exact: tanh saturated by ~30).
// Sigmoid epilogue: pp-pm = (Pm-Pp)*rcp(Pp*Pm).  Trans/pair: 37 -> 27.
// ============================================================================
__global__ __launch_bounds__(BLOCKT, 4) void density_kernel(
    const float* __restrict__ x,
    const float* __restrict__ wt,
    float* __restrict__ out)
{
    __shared__ float sW[NWS * CPB];                  // 15616 B

    const int tid  = threadIdx.x;
    const int cb   = blockIdx.x % NCG;               // channel-group
    const int tile = blockIdx.x / NCG;               // batch-tile

    const int cl = tid & (CPB - 1);                  // channel within group
    const int g  = tid >> 6;                         // row-group 0..3
    const int cg = cb * CPB + cl;                    // global channel
    const int row0 = tile * ROWS_PER_BLOCK + g * ROWS_PER_GROUP;

    // ---- issue slab-0 x loads BEFORE the staging barrier ----
    float xv[RSLAB];
    {
        const int base0 = row0 * CHN + cg;
#pragma unroll
        for (int r = 0; r < RSLAB; ++r) xv[r] = x[base0 + r * CHN];
    }

    // ---- stage this group's weights: 976 float4, coalesced ----
    {
        const float4* w4 = reinterpret_cast<const float4*>(wt);
        float4* s4 = reinterpret_cast<float4*>(sW);
        constexpr int NV = (NWS * CPB) / 4;          // 976
        for (int j = tid; j < NV; j += BLOCKT) {
            int s = j >> 4, v = j & 15;
            s4[j] = w4[(s * CHN + cb * CPB) / 4 + v];
        }
    }
    __syncthreads();

    for (int sl = 0; sl < NSLABS; ++sl) {
        // ---- prefetch next slab's x ----
        float xnext[RSLAB];
        if (sl + 1 < NSLABS) {
            const int basen = (row0 + (sl + 1) * RSLAB) * CHN + cg;
#pragma unroll
            for (int r = 0; r < RSLAB; ++r) xnext[r] = x[basen + r * CHN];
        }

        int off = 0;
        asm volatile("" : "+v"(off));                // opaque: keeps LDS reads in-slab
        const float* Wl = sW + cl + off;
#define WS(s) Wl[(s) * CPB]

        const int base = (row0 + sl * RSLAB) * CHN + cg;

        // ---- L0: shared exp2 + paired rcp across +/- branches ----
        float vp[RSLAB][3], vm[RSLAB][3];
#pragma unroll
        for (int i = 0; i < 3; ++i) {
            float w0k = WS(0 + i),  b0k = WS(3 + i);
            float cp  = WS(6 + i),  cm  = WS(9 + i);
            float gp  = WS(12 + i), gm  = WS(15 + i), t2 = WS(18 + i);
#pragma unroll
            for (int r = 0; r < RSLAB; ++r) {
                float q  = fmaf(w0k, xv[r], b0k);
                float E  = fast_exp2(fminf(q, ECLAMP));
                float Qp = fmaf(E, cp, 1.0f);
                float Qm = fmaf(E, cm, 1.0f);
                float rr = fast_rcp(Qp * Qm);
                vp[r][i] = fmaf(t2, Qm * rr, q + gp);
                vm[r][i] = fmaf(t2, Qp * rr, q + gm);
            }
        }
        // ---- L1 (fold-t1 + paired rcp) ----
        float zp[RSLAB][3], zm[RSLAB][3];
#pragma unroll
        for (int p = 0; p < 3; ++p) {
            float w0 = WS(21 + p), w1 = WS(24 + p), w2 = WS(27 + p);
            float bb = WS(30 + p), c1 = WS(33 + p), t2 = WS(36 + p);
#pragma unroll
            for (int r = 0; r < RSLAB; ++r) {
                float tq = fmaf(vp[r][2], w2, fmaf(vp[r][1], w1, fmaf(vp[r][0], w0, bb)));
                float tn = fmaf(vm[r][2], w2, fmaf(vm[r][1], w1, fmaf(vm[r][0], w0, bb)));
                float Qp = fmaf(fast_exp2(fminf(tq, ECLAMP)), c1, 1.0f);
                float Qn = fmaf(fast_exp2(fminf(tn, ECLAMP)), c1, 1.0f);
                float rr = fast_rcp(Qp * Qn);
                zp[r][p] = fmaf(t2, Qn * rr, tq);
                zm[r][p] = fmaf(t2, Qp * rr, tn);
            }
        }
        // ---- L2 (fold-t1 + paired rcp) ----
        float yp[RSLAB][3], ym[RSLAB][3];
#pragma unroll
        for (int p = 0; p < 3; ++p) {
            float w0 = WS(39 + p), w1 = WS(42 + p), w2 = WS(45 + p);
            float bb = WS(48 + p), c1 = WS(51 + p), t2 = WS(54 + p);
#pragma unroll
            for (int r = 0; r < RSLAB; ++r) {
                float tq = fmaf(zp[r][2], w2, fmaf(zp[r][1], w1, fmaf(zp[r][0], w0, bb)));
                float tn = fmaf(zm[r][2], w2, fmaf(zm[r][1], w1, fmaf(zm[r][0], w0, bb)));
                float Qp = fmaf(fast_exp2(fminf(tq, ECLAMP)), c1, 1.0f);
                float Qn = fmaf(fast_exp2(fminf(tn, ECLAMP)), c1, 1.0f);
                float rr = fast_rcp(Qp * Qn);
                yp[r][p] = fmaf(t2, Qn * rr, tq);
                ym[r][p] = fmaf(t2, Qp * rr, tn);
            }
        }
        // ---- L3 + sigmoid-diff: pp-pm = (Pm-Pp)*rcp(Pp*Pm) ----
        {
            float w30 = WS(57), w31 = WS(58), w32 = WS(59), b3n = WS(60);
#pragma unroll
            for (int r = 0; r < RSLAB; ++r) {
                float sp = fmaf(yp[r][2], w32, fmaf(yp[r][1], w31, fmaf(yp[r][0], w30, b3n)));
                float sm = fmaf(ym[r][2], w32, fmaf(ym[r][1], w31, fmaf(ym[r][0], w30, b3n)));
                float Pp = fast_exp2(fminf(sp, ECLAMP)) + 1.0f;
                float Pm = fast_exp2(fminf(sm, ECLAMP)) + 1.0f;
                out[base + r * CHN] = (Pm - Pp) * fast_rcp(Pp * Pm);
            }
        }
#undef WS
#pragma unroll
        for (int r = 0; r < RSLAB; ++r) xv[r] = xnext[r];
    }
}

extern "C" void kernel_launch(void* const* d_in, const int* in_sizes, int n_in,
                              void* d_out, int out_size, void* d_ws, size_t ws_size,
                              hipStream_t stream) {
    const float* x  = (const float*)d_in[0];
    const float* a0 = (const float*)d_in[1];
    const float* a1 = (const float*)d_in[2];
    const float* a2 = (const float*)d_in[3];
    const float* b0 = (const float*)d_in[4];
    const float* b1 = (const float*)d_in[5];
    const float* b2 = (const float*)d_in[6];
    const float* b3 = (const float*)d_in[7];
    const float* H0 = (const float*)d_in[8];
    const float* H1 = (const float*)d_in[9];
    const float* H2 = (const float*)d_in[10];
    const float* H3 = (const float*)d_in[11];
    float* out = (float*)d_out;
    float* ws  = (float*)d_ws;   // needs NWS*CHN*4 = 46.9 KB

    weights_kernel<<<(WKTHREADS + 255) / 256, 256, 0, stream>>>(
        a0, a1, a2, b0, b1, b2, b3, H0, H1, H2, H3, ws);
    density_kernel<<<NBLOCKS, BLOCKT, 0, stream>>>(x, ws, out);
}

// Round 19
// 66.080 us; speedup vs baseline: 1.0969x; 1.0969x over previous
//
#include <hip/hip_runtime.h>
#include <hip/hip_bf16.h>
#include <math.h>

#define CHN 192
#define BATCHN 65536
#define NWS 58                        // transformed-weight slots per channel (R19: 61->58)
#define CPB 64                        // channels per block (LDS = 58*64*4 = 14.5 KB)
#define NCG (CHN / CPB)               // 3 channel-groups
#define BLOCKT 256                    // 4 row-groups x 64 channels (4 waves)
#define ROWS_PER_GROUP 16
#define ROWS_PER_BLOCK 64
#define RSLAB 4
#define NSLABS (ROWS_PER_GROUP / RSLAB)        // 4
#define NBLOCKS (NCG * (BATCHN / ROWS_PER_BLOCK))  // 3*1024 = 3072

#define KSCALE 2.885390081777926f    // 2*log2(e)
#define LOG2E  1.4426950408889634f

// ---- fast device math -------------------------------------------------------
__device__ __forceinline__ float fast_rcp(float x)  { return __builtin_amdgcn_rcpf(x); }
__device__ __forceinline__ float fast_exp2(float x) { return __builtin_amdgcn_exp2f(x); }

__device__ __forceinline__ float softplus_acc(float h) {
    if (h > 20.0f) return h;
    return log1pf(expf(h));
}

// ============================================================================
// Kernel A (R19): parallel across (channel x layer-unit) = 2304 threads.
// Scaled domain: v' = K*v, K = 2*log2(e); exp2(t') = e^(2t);
// tanh(t) = 1 - 2*rcp(exp2(t')+1)  (inf-safe: rcp(inf)=0).
// R19 gp/gm-fold: L0 emits vp = fma(T2_0, rp, q) (no +gp); the constants
// gp[i] = 0.5*w0k[i] + K*t0[i], gm[i] = -0.5*w0k[i] + K*t0[i] are folded into
// branch-specific L1 biases: BBP1[p] = (K*b1[p]+t1k1[p]) + Sum_i W1[i][p]*gp[i],
// BBM1[p] likewise with gm.  -6 VALU/pair, -3 LDS reads/slab.
// slot map (ws[s*CHN + c]):
//   0-2 W0K | 3-5 B0K | 6-8 cp | 9-11 cm | 12-14 T2_0
//   15-23 W1[i*3+p] | 24-26 BBP1 | 27-29 BBM1 | 30-32 C1_1 | 33-35 T2_1
//   36-44 W2[i*3+p] | 45-47 BBT2 | 48-50 C1_2 | 51-53 T2_2
//   54-56 W3n | 57 b3n
// ============================================================================
#define WKTHREADS (12 * CHN)          // 2304
__global__ __launch_bounds__(256) void weights_kernel(
    const float* __restrict__ a0, const float* __restrict__ a1, const float* __restrict__ a2,
    const float* __restrict__ b0, const float* __restrict__ b1, const float* __restrict__ b2,
    const float* __restrict__ b3,
    const float* __restrict__ H0, const float* __restrict__ H1, const float* __restrict__ H2,
    const float* __restrict__ H3,
    float* __restrict__ ws)
{
    const int g = blockIdx.x * 256 + threadIdx.x;
    if (g >= WKTHREADS) return;
    const int c = g % CHN;
    const int u = g / CHN;            // 0..11 (wave-uniform)
    const int l = u / 3, i = u % 3;

    if (l == 0) {
        float w0k  = KSCALE * softplus_acc(H0[c * 3 + i]);
        float h    = 0.5f * w0k;
        float t1k0 = KSCALE * tanhf(a0[c * 3 + i]);
        ws[(0  + i) * CHN + c] = w0k;
        ws[(3  + i) * CHN + c] = KSCALE * b0[c * 3 + i];
        ws[(6  + i) * CHN + c] = exp2f(h);
        ws[(9  + i) * CHN + c] = exp2f(-h);
        ws[(12 + i) * CHN + c] = -2.0f * t1k0;                    // T2_0
        (void)t1k0;
    } else if (l == 1) {
        const int p = i;
        // W1 row p (slots 15 + p*3 + k are [i=p][k]? layout is [i*3+p]: row i)
        // This thread writes W1 ROW i=p: slots 15 + p*3 + k  (= W1[p][k])
#pragma unroll
        for (int k = 0; k < 3; ++k)
            ws[(15 + 3 * p + k) * CHN + c] = softplus_acc(H1[c * 9 + 3 * p + k]);
        // Branch-folded biases for OUTPUT unit p: need W1 COLUMN p = W1[k][p]
        float t1k1 = KSCALE * tanhf(a1[c * 3 + p]);
        float bbt  = KSCALE * b1[c * 3 + p] + t1k1;
        float accp = bbt, accm = bbt;
#pragma unroll
        for (int k = 0; k < 3; ++k) {
            float w1kp = softplus_acc(H1[c * 9 + 3 * k + p]);     // W1[k][p]
            float w0k  = KSCALE * softplus_acc(H0[c * 3 + k]);
            float t1k0 = KSCALE * tanhf(a0[c * 3 + k]);
            float gp   =  0.5f * w0k + t1k0;
            float gm   = -0.5f * w0k + t1k0;
            accp = fmaf(w1kp, gp, accp);
            accm = fmaf(w1kp, gm, accm);
        }
        ws[(24 + p) * CHN + c] = accp;                            // BBP1
        ws[(27 + p) * CHN + c] = accm;                            // BBM1
        ws[(30 + p) * CHN + c] = exp2f(-t1k1);                    // C1_1
        ws[(33 + p) * CHN + c] = -2.0f * t1k1;                    // T2_1
    } else if (l == 2) {
        float t1k2 = KSCALE * tanhf(a2[c * 3 + i]);
        ws[(45 + i) * CHN + c] = KSCALE * b2[c * 3 + i] + t1k2;   // BBT2
        ws[(48 + i) * CHN + c] = exp2f(-t1k2);                    // C1_2
        ws[(51 + i) * CHN + c] = -2.0f * t1k2;                    // T2_2
#pragma unroll
        for (int k = 0; k < 3; ++k)
            ws[(36 + 3 * i + k) * CHN + c] = softplus_acc(H2[c * 9 + 3 * i + k]);
    } else {
        ws[(54 + i) * CHN + c] = -0.5f * softplus_acc(H3[c * 3 + i]);
        if (i == 0) ws[57 * CHN + c] = -LOG2E * b3[c];
    }
}

// ============================================================================
// Kernel B (R19): R17 structure, gp/gm folded out of L0.
// ============================================================================
__global__ __launch_bounds__(BLOCKT, 4) void density_kernel(
    const float* __restrict__ x,
    const float* __restrict__ wt,
    float* __restrict__ out)
{
    __shared__ float sW[NWS * CPB];                  // 14848 B

    const int tid  = threadIdx.x;
    const int cb   = blockIdx.x % NCG;               // channel-group
    const int tile = blockIdx.x / NCG;               // batch-tile

    const int cl = tid & (CPB - 1);                  // channel within group
    const int g  = tid >> 6;                         // row-group 0..3
    const int cg = cb * CPB + cl;                    // global channel
    const int row0 = tile * ROWS_PER_BLOCK + g * ROWS_PER_GROUP;

    // ---- issue slab-0 x loads BEFORE the staging barrier ----
    float xv[RSLAB];
    {
        const int base0 = row0 * CHN + cg;
#pragma unroll
        for (int r = 0; r < RSLAB; ++r) xv[r] = x[base0 + r * CHN];
    }

    // ---- stage this group's weights: 928 float4, coalesced ----
    {
        const float4* w4 = reinterpret_cast<const float4*>(wt);
        float4* s4 = reinterpret_cast<float4*>(sW);
        constexpr int NV = (NWS * CPB) / 4;          // 928
        for (int j = tid; j < NV; j += BLOCKT) {
            int s = j >> 4, v = j & 15;
            s4[j] = w4[(s * CHN + cb * CPB) / 4 + v];
        }
    }
    __syncthreads();

    for (int sl = 0; sl < NSLABS; ++sl) {
        // ---- prefetch next slab's x ----
        float xnext[RSLAB];
        if (sl + 1 < NSLABS) {
            const int basen = (row0 + (sl + 1) * RSLAB) * CHN + cg;
#pragma unroll
            for (int r = 0; r < RSLAB; ++r) xnext[r] = x[basen + r * CHN];
        }

        int off = 0;
        asm volatile("" : "+v"(off));                // opaque: keeps LDS reads in-slab
        const float* Wl = sW + cl + off;
#define WS(s) Wl[(s) * CPB]

        const int base = (row0 + sl * RSLAB) * CHN + cg;

        // ---- L0: shared exp2; gp/gm folded into L1 biases ----
        float vp[RSLAB][3], vm[RSLAB][3];
#pragma unroll
        for (int i = 0; i < 3; ++i) {
            float w0k = WS(0 + i),  b0k = WS(3 + i);
            float cp  = WS(6 + i),  cm  = WS(9 + i), t2 = WS(12 + i);
#pragma unroll
            for (int r = 0; r < RSLAB; ++r) {
                float q  = fmaf(w0k, xv[r], b0k);
                float E  = fast_exp2(q);
                float rp = fast_rcp(fmaf(E, cp, 1.0f));
                float rm = fast_rcp(fmaf(E, cm, 1.0f));
                vp[r][i] = fmaf(t2, rp, q);
                vm[r][i] = fmaf(t2, rm, q);
            }
        }
        // ---- L1 (fold-t1 + branch-specific folded biases) ----
        float zp[RSLAB][3], zm[RSLAB][3];
#pragma unroll
        for (int p = 0; p < 3; ++p) {
            float w0 = WS(15 + p), w1 = WS(18 + p), w2 = WS(21 + p);   // W1[i][p], i=0..2
            float bbp = WS(24 + p), bbm = WS(27 + p);
            float c1  = WS(30 + p), t2  = WS(33 + p);
#pragma unroll
            for (int r = 0; r < RSLAB; ++r) {
                float tq = fmaf(vp[r][2], w2, fmaf(vp[r][1], w1, fmaf(vp[r][0], w0, bbp)));
                float tn = fmaf(vm[r][2], w2, fmaf(vm[r][1], w1, fmaf(vm[r][0], w0, bbm)));
                float rp = fast_rcp(fmaf(fast_exp2(tq), c1, 1.0f));
                float rm = fast_rcp(fmaf(fast_exp2(tn), c1, 1.0f));
                zp[r][p] = fmaf(t2, rp, tq);
                zm[r][p] = fmaf(t2, rm, tn);
            }
        }
        // ---- L2 (fold-t1 form) ----
        float yp[RSLAB][3], ym[RSLAB][3];
#pragma unroll
        for (int p = 0; p < 3; ++p) {
            float w0 = WS(36 + p), w1 = WS(39 + p), w2 = WS(42 + p);
            float bb = WS(45 + p), c1 = WS(48 + p), t2 = WS(51 + p);
#pragma unroll
            for (int r = 0; r < RSLAB; ++r) {
                float tq = fmaf(zp[r][2], w2, fmaf(zp[r][1], w1, fmaf(zp[r][0], w0, bb)));
                float tn = fmaf(zm[r][2], w2, fmaf(zm[r][1], w1, fmaf(zm[r][0], w0, bb)));
                float rp = fast_rcp(fmaf(fast_exp2(tq), c1, 1.0f));
                float rm = fast_rcp(fmaf(fast_exp2(tn), c1, 1.0f));
                yp[r][p] = fmaf(t2, rp, tq);
                ym[r][p] = fmaf(t2, rm, tn);
            }
        }
        // ---- L3 + sigmoid (s'' = -log2e*s; p = rcp(exp2(s'')+1)) ----
        {
            float w30 = WS(54), w31 = WS(55), w32 = WS(56), b3n = WS(57);
#pragma unroll
            for (int r = 0; r < RSLAB; ++r) {
                float sp = fmaf(yp[r][2], w32, fmaf(yp[r][1], w31, fmaf(yp[r][0], w30, b3n)));
                float sm = fmaf(ym[r][2], w32, fmaf(ym[r][1], w31, fmaf(ym[r][0], w30, b3n)));
                float pp = fast_rcp(fast_exp2(sp) + 1.0f);
                float pm = fast_rcp(fast_exp2(sm) + 1.0f);
                out[base + r * CHN] = pp - pm;
            }
        }
#undef WS
#pragma unroll
        for (int r = 0; r < RSLAB; ++r) xv[r] = xnext[r];
    }
}

extern "C" void kernel_launch(void* const* d_in, const int* in_sizes, int n_in,
                              void* d_out, int out_size, void* d_ws, size_t ws_size,
                              hipStream_t stream) {
    const float* x  = (const float*)d_in[0];
    const float* a0 = (const float*)d_in[1];
    const float* a1 = (const float*)d_in[2];
    const float* a2 = (const float*)d_in[3];
    const float* b0 = (const float*)d_in[4];
    const float* b1 = (const float*)d_in[5];
    const float* b2 = (const float*)d_in[6];
    const float* b3 = (const float*)d_in[7];
    const float* H0 = (const float*)d_in[8];
    const float* H1 = (const float*)d_in[9];
    const float* H2 = (const float*)d_in[10];
    const float* H3 = (const float*)d_in[11];
    float* out = (float*)d_out;
    float* ws  = (float*)d_ws;   // needs NWS*CHN*4 = 44.5 KB

    weights_kernel<<<(WKTHREADS + 255) / 256, 256, 0, stream>>>(
        a0, a1, a2, b0, b1, b2, b3, H0, H1, H2, H3, ws);
    density_kernel<<<NBLOCKS, BLOCKT, 0, stream>>>(x, ws, out);
}

// Round 20
// 66.013 us; speedup vs baseline: 1.0980x; 1.0010x over previous
//
#include <hip/hip_runtime.h>
#include <hip/hip_bf16.h>
#include <math.h>

#define CHN 192
#define BATCHN 65536
#define NWS 58                        // transformed-weight slots per channel
#define CPB 64                        // channels per block (LDS = 58*64*4 = 14.5 KB)
#define NCG (CHN / CPB)               // 3 channel-groups
#define BLOCKT 256                    // 4 row-groups x 64 channels (4 waves)
#define ROWS_PER_GROUP 16
#define ROWS_PER_BLOCK 64
#define RSLAB 4
#define NSLABS (ROWS_PER_GROUP / RSLAB)        // 4
#define NBLOCKS (NCG * (BATCHN / ROWS_PER_BLOCK))  // 3*1024 = 3072

#define KSCALE 2.885390081777926f    // 2*log2(e)
#define LOG2E  1.4426950408889634f

// ---- fast device math -------------------------------------------------------
__device__ __forceinline__ float fast_rcp(float x)  { return __builtin_amdgcn_rcpf(x); }
__device__ __forceinline__ float fast_exp2(float x) { return __builtin_amdgcn_exp2f(x); }

__device__ __forceinline__ float softplus_acc(float h) {
    if (h > 20.0f) return h;
    return log1pf(expf(h));
}

// ============================================================================
// Kernel A (R19 form): parallel across (channel x layer-unit) = 2304 threads.
// Scaled domain: v' = K*v, K = 2*log2(e); exp2(t') = e^(2t);
// tanh(t) = 1 - 2*rcp(exp2(t')+1)  (inf-safe: rcp(inf)=0).
// gp/gm-fold: L0 emits vp = fma(T2_0, rp, q); gp/gm folded into branch-
// specific L1 biases BBP1/BBM1.
// slot map (ws[s*CHN + c]):
//   0-2 W0K | 3-5 B0K | 6-8 cp | 9-11 cm | 12-14 T2_0
//   15-23 W1[i*3+p] | 24-26 BBP1 | 27-29 BBM1 | 30-32 C1_1 | 33-35 T2_1
//   36-44 W2[i*3+p] | 45-47 BBT2 | 48-50 C1_2 | 51-53 T2_2
//   54-56 W3n | 57 b3n
// ============================================================================
#define WKTHREADS (12 * CHN)          // 2304
__global__ __launch_bounds__(256) void weights_kernel(
    const float* __restrict__ a0, const float* __restrict__ a1, const float* __restrict__ a2,
    const float* __restrict__ b0, const float* __restrict__ b1, const float* __restrict__ b2,
    const float* __restrict__ b3,
    const float* __restrict__ H0, const float* __restrict__ H1, const float* __restrict__ H2,
    const float* __restrict__ H3,
    float* __restrict__ ws)
{
    const int g = blockIdx.x * 256 + threadIdx.x;
    if (g >= WKTHREADS) return;
    const int c = g % CHN;
    const int u = g / CHN;            // 0..11 (wave-uniform)
    const int l = u / 3, i = u % 3;

    if (l == 0) {
        float w0k  = KSCALE * softplus_acc(H0[c * 3 + i]);
        float h    = 0.5f * w0k;
        float t1k0 = KSCALE * tanhf(a0[c * 3 + i]);
        ws[(0  + i) * CHN + c] = w0k;
        ws[(3  + i) * CHN + c] = KSCALE * b0[c * 3 + i];
        ws[(6  + i) * CHN + c] = exp2f(h);
        ws[(9  + i) * CHN + c] = exp2f(-h);
        ws[(12 + i) * CHN + c] = -2.0f * t1k0;                    // T2_0
    } else if (l == 1) {
        const int p = i;
#pragma unroll
        for (int k = 0; k < 3; ++k)
            ws[(15 + 3 * p + k) * CHN + c] = softplus_acc(H1[c * 9 + 3 * p + k]);
        float t1k1 = KSCALE * tanhf(a1[c * 3 + p]);
        float bbt  = KSCALE * b1[c * 3 + p] + t1k1;
        float accp = bbt, accm = bbt;
#pragma unroll
        for (int k = 0; k < 3; ++k) {
            float w1kp = softplus_acc(H1[c * 9 + 3 * k + p]);     // W1[k][p]
            float w0k  = KSCALE * softplus_acc(H0[c * 3 + k]);
            float t1k0 = KSCALE * tanhf(a0[c * 3 + k]);
            float gp   =  0.5f * w0k + t1k0;
            float gm   = -0.5f * w0k + t1k0;
            accp = fmaf(w1kp, gp, accp);
            accm = fmaf(w1kp, gm, accm);
        }
        ws[(24 + p) * CHN + c] = accp;                            // BBP1
        ws[(27 + p) * CHN + c] = accm;                            // BBM1
        ws[(30 + p) * CHN + c] = exp2f(-t1k1);                    // C1_1
        ws[(33 + p) * CHN + c] = -2.0f * t1k1;                    // T2_1
    } else if (l == 2) {
        float t1k2 = KSCALE * tanhf(a2[c * 3 + i]);
        ws[(45 + i) * CHN + c] = KSCALE * b2[c * 3 + i] + t1k2;   // BBT2
        ws[(48 + i) * CHN + c] = exp2f(-t1k2);                    // C1_2
        ws[(51 + i) * CHN + c] = -2.0f * t1k2;                    // T2_2
#pragma unroll
        for (int k = 0; k < 3; ++k)
            ws[(36 + 3 * i + k) * CHN + c] = softplus_acc(H2[c * 9 + 3 * i + k]);
    } else {
        ws[(54 + i) * CHN + c] = -0.5f * softplus_acc(H3[c * 3 + i]);
        if (i == 0) ws[57 * CHN + c] = -LOG2E * b3[c];
    }
}

// ============================================================================
// Kernel B (R20): R19 verbatim except __launch_bounds__(256, 6).
// Occupancy axis: 4 blocks/CU = 47% occ / 80% busy (R13/R19); 8 blocks/CU
// regressed via L2 write-thrash (R14). 6 is the untested midpoint.
// ============================================================================
__global__ __launch_bounds__(BLOCKT, 6) void density_kernel(
    const float* __restrict__ x,
    const float* __restrict__ wt,
    float* __restrict__ out)
{
    __shared__ float sW[NWS * CPB];                  // 14848 B

    const int tid  = threadIdx.x;
    const int cb   = blockIdx.x % NCG;               // channel-group
    const int tile = blockIdx.x / NCG;               // batch-tile

    const int cl = tid & (CPB - 1);                  // channel within group
    const int g  = tid >> 6;                         // row-group 0..3
    const int cg = cb * CPB + cl;                    // global channel
    const int row0 = tile * ROWS_PER_BLOCK + g * ROWS_PER_GROUP;

    // ---- issue slab-0 x loads BEFORE the staging barrier ----
    float xv[RSLAB];
    {
        const int base0 = row0 * CHN + cg;
#pragma unroll
        for (int r = 0; r < RSLAB; ++r) xv[r] = x[base0 + r * CHN];
    }

    // ---- stage this group's weights: 928 float4, coalesced ----
    {
        const float4* w4 = reinterpret_cast<const float4*>(wt);
        float4* s4 = reinterpret_cast<float4*>(sW);
        constexpr int NV = (NWS * CPB) / 4;          // 928
        for (int j = tid; j < NV; j += BLOCKT) {
            int s = j >> 4, v = j & 15;
            s4[j] = w4[(s * CHN + cb * CPB) / 4 + v];
        }
    }
    __syncthreads();

    for (int sl = 0; sl < NSLABS; ++sl) {
        // ---- prefetch next slab's x ----
        float xnext[RSLAB];
        if (sl + 1 < NSLABS) {
            const int basen = (row0 + (sl + 1) * RSLAB) * CHN + cg;
#pragma unroll
            for (int r = 0; r < RSLAB; ++r) xnext[r] = x[basen + r * CHN];
        }

        int off = 0;
        asm volatile("" : "+v"(off));                // opaque: keeps LDS reads in-slab
        const float* Wl = sW + cl + off;
#define WS(s) Wl[(s) * CPB]

        const int base = (row0 + sl * RSLAB) * CHN + cg;

        // ---- L0: shared exp2; gp/gm folded into L1 biases ----
        float vp[RSLAB][3], vm[RSLAB][3];
#pragma unroll
        for (int i = 0; i < 3; ++i) {
            float w0k = WS(0 + i),  b0k = WS(3 + i);
            float cp  = WS(6 + i),  cm  = WS(9 + i), t2 = WS(12 + i);
#pragma unroll
            for (int r = 0; r < RSLAB; ++r) {
                float q  = fmaf(w0k, xv[r], b0k);
                float E  = fast_exp2(q);
                float rp = fast_rcp(fmaf(E, cp, 1.0f));
                float rm = fast_rcp(fmaf(E, cm, 1.0f));
                vp[r][i] = fmaf(t2, rp, q);
                vm[r][i] = fmaf(t2, rm, q);
            }
        }
        // ---- L1 (fold-t1 + branch-specific folded biases) ----
        float zp[RSLAB][3], zm[RSLAB][3];
#pragma unroll
        for (int p = 0; p < 3; ++p) {
            float w0 = WS(15 + p), w1 = WS(18 + p), w2 = WS(21 + p);   // W1[i][p]
            float bbp = WS(24 + p), bbm = WS(27 + p);
            float c1  = WS(30 + p), t2  = WS(33 + p);
#pragma unroll
            for (int r = 0; r < RSLAB; ++r) {
                float tq = fmaf(vp[r][2], w2, fmaf(vp[r][1], w1, fmaf(vp[r][0], w0, bbp)));
                float tn = fmaf(vm[r][2], w2, fmaf(vm[r][1], w1, fmaf(vm[r][0], w0, bbm)));
                float rp = fast_rcp(fmaf(fast_exp2(tq), c1, 1.0f));
                float rm = fast_rcp(fmaf(fast_exp2(tn), c1, 1.0f));
                zp[r][p] = fmaf(t2, rp, tq);
                zm[r][p] = fmaf(t2, rm, tn);
            }
        }
        // ---- L2 (fold-t1 form) ----
        float yp[RSLAB][3], ym[RSLAB][3];
#pragma unroll
        for (int p = 0; p < 3; ++p) {
            float w0 = WS(36 + p), w1 = WS(39 + p), w2 = WS(42 + p);
            float bb = WS(45 + p), c1 = WS(48 + p), t2 = WS(51 + p);
#pragma unroll
            for (int r = 0; r < RSLAB; ++r) {
                float tq = fmaf(zp[r][2], w2, fmaf(zp[r][1], w1, fmaf(zp[r][0], w0, bb)));
                float tn = fmaf(zm[r][2], w2, fmaf(zm[r][1], w1, fmaf(zm[r][0], w0, bb)));
                float rp = fast_rcp(fmaf(fast_exp2(tq), c1, 1.0f));
                float rm = fast_rcp(fmaf(fast_exp2(tn), c1, 1.0f));
                yp[r][p] = fmaf(t2, rp, tq);
                ym[r][p] = fmaf(t2, rm, tn);
            }
        }
        // ---- L3 + sigmoid (s'' = -log2e*s; p = rcp(exp2(s'')+1)) ----
        {
            float w30 = WS(54), w31 = WS(55), w32 = WS(56), b3n = WS(57);
#pragma unroll
            for (int r = 0; r < RSLAB; ++r) {
                float sp = fmaf(yp[r][2], w32, fmaf(yp[r][1], w31, fmaf(yp[r][0], w30, b3n)));
                float sm = fmaf(ym[r][2], w32, fmaf(ym[r][1], w31, fmaf(ym[r][0], w30, b3n)));
                float pp = fast_rcp(fast_exp2(sp) + 1.0f);
                float pm = fast_rcp(fast_exp2(sm) + 1.0f);
                out[base + r * CHN] = pp - pm;
            }
        }
#undef WS
#pragma unroll
        for (int r = 0; r < RSLAB; ++r) xv[r] = xnext[r];
    }
}

extern "C" void kernel_launch(void* const* d_in, const int* in_sizes, int n_in,
                              void* d_out, int out_size, void* d_ws, size_t ws_size,
                              hipStream_t stream) {
    const float* x  = (const float*)d_in[0];
    const float* a0 = (const float*)d_in[1];
    const float* a1 = (const float*)d_in[2];
    const float* a2 = (const float*)d_in[3];
    const float* b0 = (const float*)d_in[4];
    const float* b1 = (const float*)d_in[5];
    const float* b2 = (const float*)d_in[6];
    const float* b3 = (const float*)d_in[7];
    const float* H0 = (const float*)d_in[8];
    const float* H1 = (const float*)d_in[9];
    const float* H2 = (const float*)d_in[10];
    const float* H3 = (const float*)d_in[11];
    float* out = (float*)d_out;
    float* ws  = (float*)d_ws;   // needs NWS*CHN*4 = 44.5 KB

    weights_kernel<<<(WKTHREADS + 255) / 256, 256, 0, stream>>>(
        a0, a1, a2, b0, b1, b2, b3, H0, H1, H2, H3, ws);
    density_kernel<<<NBLOCKS, BLOCKT, 0, stream>>>(x, ws, out);
}